// Round 8
// baseline (860.250 us; speedup 1.0000x reference)
//
#include <hip/hip_runtime.h>
#include <hip/hip_bf16.h>

#define DS 32
#define DIM 512
#define NH 8
#define HD 64
#define NE 4
#define NC 2
#define BB 8
#define LL 2
#define FFD 2048
#define S2 1024
#define SS 1028
#define MM (BB*SS)          // 8224 rows
#define KE 160              // extended K dim for bias-folded attention
#define EXT ((size_t)BB*NH*SS*KE)

typedef __attribute__((ext_vector_type(8))) short s16x8;
typedef __attribute__((ext_vector_type(4))) float f32x4;
typedef unsigned short u16;

__device__ __forceinline__ u16 f2b(float f) {
    __hip_bfloat16 h = __float2bfloat16(f);
    return *reinterpret_cast<u16*>(&h);
}
__device__ __forceinline__ float b2f(u16 u) {
    __hip_bfloat16 h;
    *reinterpret_cast<u16*>(&h) = u;
    return __bfloat162float(h);
}

// async global->LDS 16B copy. LDS dest = wave-uniform base + lane*16.
// AS casts via uintptr_t (CK pattern): AS0->AS3 is low-32-bit truncate on AMDGPU.
__device__ __forceinline__ void gload_lds16(const void* g, void* l) {
    __builtin_amdgcn_global_load_lds(
        (const __attribute__((address_space(1))) void*)(uintptr_t)g,
        (__attribute__((address_space(3))) void*)(uint32_t)(uintptr_t)l,
        16, 0, 0);
}

// ---------------- embed ----------------
__global__ void embed_kernel(const float* __restrict__ x, const float* __restrict__ patches,
                             const float* __restrict__ We, const float* __restrict__ be,
                             float* __restrict__ h) {
    int row = blockIdx.x;
    int b = row / SS, i = row % SS;
    float* hr = h + (size_t)row * DIM;
    if (i < NE) {
        const float* xr = x + (size_t)b*NE*DIM + (size_t)i*DIM;
        for (int d = threadIdx.x; d < DIM; d += blockDim.x) hr[d] = xr[d];
    } else {
        int p = i - NE;
        float c0 = patches[(size_t)b*3*S2 + 0*S2 + p];
        float c1 = patches[(size_t)b*3*S2 + 1*S2 + p];
        float c2 = patches[(size_t)b*3*S2 + 2*S2 + p];
        for (int d = threadIdx.x; d < DIM; d += blockDim.x)
            hr[d] = be[d] + c0*We[d] + c1*We[DIM+d] + c2*We[2*DIM+d];
    }
}

// ---------------- layernorm: f32 in -> bf16 out ----------------
__global__ void ln_kernel(const float* __restrict__ in, u16* __restrict__ out,
                          const float* __restrict__ g, const float* __restrict__ bt) {
    int row = blockIdx.x;
    const float* xr = in + (size_t)row*DIM;
    int t = threadIdx.x;
    float v0 = xr[t], v1 = xr[t+256];
    float s = v0 + v1, s2 = v0*v0 + v1*v1;
    for (int off = 32; off; off >>= 1) { s += __shfl_down(s, off); s2 += __shfl_down(s2, off); }
    __shared__ float ps[4], ps2[4];
    int wid = t >> 6, lane = t & 63;
    if (lane == 0) { ps[wid] = s; ps2[wid] = s2; }
    __syncthreads();
    if (t == 0) { ps[0] = ps[0]+ps[1]+ps[2]+ps[3]; ps2[0] = ps2[0]+ps2[1]+ps2[2]+ps2[3]; }
    __syncthreads();
    float mean = ps[0] * (1.0f/DIM);
    float var  = ps2[0] * (1.0f/DIM) - mean*mean;
    float inv = rsqrtf(var + 1e-5f);
    u16* orow = out + (size_t)row*DIM;
    orow[t]     = f2b((v0 - mean)*inv*g[t]     + bt[t]);
    orow[t+256] = f2b((v1 - mean)*inv*g[t+256] + bt[t+256]);
}

// ---------------- transpose+convert: src f32 [R][C] -> dst bf16 [C][R] ----------------
__global__ void transp_kernel(const float* __restrict__ src, u16* __restrict__ dst,
                              int R, int C) {
    __shared__ float tile[32][33];
    int c0 = blockIdx.x*32, r0 = blockIdx.y*32;
    int tx = threadIdx.x & 31, ty = threadIdx.x >> 5;   // 32 x 8
    #pragma unroll
    for (int ii = 0; ii < 4; ii++)
        tile[ty + ii*8][tx] = src[(size_t)(r0 + ty + ii*8)*C + c0 + tx];
    __syncthreads();
    #pragma unroll
    for (int ii = 0; ii < 4; ii++)
        dst[(size_t)(c0 + ty + ii*8)*R + r0 + tx] = f2b(tile[tx][ty + ii*8]);
}

__global__ void cat_bias_kernel(const float* __restrict__ bq, const float* __restrict__ bk,
                                const float* __restrict__ bv, float* __restrict__ out) {
    int t = blockIdx.x*256 + threadIdx.x;
    if (t >= 1536) return;
    out[t] = (t < 512) ? bq[t] : (t < 1024 ? bk[t-512] : bv[t-1024]);
}

// ---------------- bf16 MFMA GEMM, global_load_lds staging, linear LDS ----------------
// 1D grid with bijective XCD chunking (m204); Nt = N/128 passed explicitly.
// MODE: 0 = f32 out + residual, 1 = bf16 out (RELU opt), 2 = qkv split (Cb=q, kd, vd)
template<int MODE, int RELU>
__global__ __launch_bounds__(256) void mfma_gemm(
    const u16* __restrict__ A, const u16* __restrict__ WT,
    const float* __restrict__ bias, const float* __restrict__ res,
    float* __restrict__ Cf, u16* __restrict__ Cb,
    u16* __restrict__ kd, u16* __restrict__ vd,
    int M, int N, int K, int Nt)
{
    __shared__ __align__(16) u16 a_lds[128*64];
    __shared__ __align__(16) u16 b_lds[128*64];
    int nwg = gridDim.x;
    int q8 = nwg >> 3, r8 = nwg & 7;
    int bid = blockIdx.x;
    int xcd = bid & 7, loc = bid >> 3;
    int g = (xcd < r8 ? xcd*(q8+1) : r8*(q8+1) + (xcd - r8)*q8) + loc;
    int row0 = (g / Nt) * 128, col0 = (g % Nt) * 128;

    int tid = threadIdx.x, w = tid>>6, l = tid&63;
    int lg = l>>4, lc = l&15;
    int wr = (w>>1)*64, wc = (w&1)*64;
    f32x4 acc[4][4];
    #pragma unroll
    for (int m = 0; m < 4; m++)
        #pragma unroll
        for (int n = 0; n < 4; n++) { f32x4 z = {0.f,0.f,0.f,0.f}; acc[m][n] = z; }

    int c16 = l & 7;                       // element's 8-u16 chunk within the 64-col row
    for (int k0 = 0; k0 < K; k0 += 64) {
        #pragma unroll
        for (int p = 0; p < 4; p++) {
            int e = p*256 + tid;           // 16B-unit index; e*8 u16 = dest offset (linear)
            int r = e >> 3;
            int ra = row0 + r; if (ra > M-1) ra = M-1;
            gload_lds16(A  + (size_t)ra*K + k0 + c16*8,          a_lds + p*2048 + w*512);
            gload_lds16(WT + (size_t)(col0 + r)*K + k0 + c16*8,  b_lds + p*2048 + w*512);
        }
        __syncthreads();                   // drains vmcnt (compiler-inserted)
        #pragma unroll
        for (int ks = 0; ks < 2; ks++) {
            int cb = ks*32 + lg*8;
            s16x8 af[4], bfr[4];
            #pragma unroll
            for (int m = 0; m < 4; m++)
                af[m] = *(const s16x8*)(a_lds + (wr + m*16 + lc)*64 + cb);
            #pragma unroll
            for (int n = 0; n < 4; n++)
                bfr[n] = *(const s16x8*)(b_lds + (wc + n*16 + lc)*64 + cb);
            #pragma unroll
            for (int m = 0; m < 4; m++)
                #pragma unroll
                for (int n = 0; n < 4; n++)
                    acc[m][n] = __builtin_amdgcn_mfma_f32_16x16x32_bf16(af[m], bfr[n], acc[m][n], 0, 0, 0);
        }
        __syncthreads();
    }
    #pragma unroll
    for (int m = 0; m < 4; m++) {
        #pragma unroll
        for (int r = 0; r < 4; r++) {
            int row = row0 + wr + m*16 + lg*4 + r;
            if (row >= M) continue;
            #pragma unroll
            for (int n = 0; n < 4; n++) {
                int col = col0 + wc + n*16 + lc;
                float v = acc[m][n][r] + bias[col];
                if (MODE == 2) {
                    int which = col >> 9, c2 = col & 511;
                    if (which == 0) v *= 0.125f;
                    u16* dst = (which == 0) ? Cb : (which == 1 ? kd : vd);
                    dst[(size_t)row*512 + c2] = f2b(v);
                } else if (MODE == 1) {
                    if (RELU) v = fmaxf(v, 0.f);
                    Cb[(size_t)row*N + col] = f2b(v);
                } else {
                    Cf[(size_t)row*N + col] = v + res[(size_t)row*N + col];
                }
            }
        }
    }
}

// ---------------- qp: qp0/1[bh,i] = q[b,i,h,:]·pad0/1 (f32 out) ----------------
__global__ void qp_kernel(const u16* __restrict__ q, const float* __restrict__ pad0,
                          const float* __restrict__ pad1, float* __restrict__ qp0,
                          float* __restrict__ qp1) {
    int idx = blockIdx.x * blockDim.x + threadIdx.x;
    if (idx >= BB*NH*SS) return;
    int i = idx % SS; int bh = idx / SS; int b = bh >> 3, hh = bh & 7;
    const u16* qr = q + ((size_t)(b*SS + i))*DIM + hh*HD;
    float a0 = 0.f, a1 = 0.f;
    #pragma unroll 8
    for (int d = 0; d < HD; d++) { float qv = b2f(qr[d]); a0 += qv*pad0[d]; a1 += qv*pad1[d]; }
    qp0[idx] = a0; qp1[idx] = a1;
}

// ---------------- Q_ext skeleton (vectorized, 8 u16/thread) ----------------
__global__ void qext_kernel(const u16* __restrict__ qb, const float* __restrict__ qp0,
                            const float* __restrict__ qp1, u16* __restrict__ Qe) {
    size_t id = (size_t)blockIdx.x*256 + threadIdx.x;     // unit index (8 u16 each)
    if (id >= EXT/8) return;
    int u = (int)(id % 20);
    size_t row = id / 20;                                  // bh*SS + i
    int bh = (int)(row / SS), i = (int)(row - (size_t)bh*SS);
    int b = bh >> 3, hh = bh & 7;
    s16x8 val = {0,0,0,0,0,0,0,0};
    if (u < 8) {
        val = *(const s16x8*)(qb + ((size_t)(b*SS + i))*DIM + hh*HD + u*8);
    } else if (u == 16) {
        float v128 = (i < NE) ? qp0[bh*SS + i] : qp1[bh*SS + i];
        float v129 = (i < NE) ? qp1[bh*SS + i] : 0.f;
        val[0] = (short)f2b(v128);
        val[1] = (short)f2b(v129);
    }
    *(s16x8*)(Qe + row*KE + u*8) = val;
}

// ---------------- K_ext build (vectorized) ----------------
__global__ void kext_kernel(const u16* __restrict__ kb, u16* __restrict__ Ke) {
    size_t id = (size_t)blockIdx.x*256 + threadIdx.x;
    if (id >= EXT/8) return;
    int u = (int)(id % 20);
    size_t row = id / 20;
    int bh = (int)(row / SS), j = (int)(row - (size_t)bh*SS);
    int b = bh >> 3, hh = bh & 7;
    const short ONE = 0x3F80;
    s16x8 val = {0,0,0,0,0,0,0,0};
    if (u < 8) {
        val = *(const s16x8*)(kb + ((size_t)(b*SS + j))*DIM + hh*HD + u*8);
    } else {
        int pj = j - NE, cj = pj & 31, rj = pj >> 5;
        #pragma unroll
        for (int e = 0; e < 8; e++) {
            int t = u*8 + e;
            short v = 0;
            if (j >= NE) {
                if (t < 96)       { if (cj == t-64) v = ONE; }
                else if (t < 128) { if (rj == t-96) v = ONE; }
                else if (t == 129) v = ONE;
            } else if (t == 128) v = ONE;
            val[e] = v;
        }
    }
    *(s16x8*)(Ke + row*KE + u*8) = val;
}

// ---------------- qx/qy via MFMA, windows scattered directly into Q_ext ----------------
__global__ __launch_bounds__(256) void qxy_mfma(
    const u16* __restrict__ q, const float* __restrict__ x_emb,
    const float* __restrict__ y_emb, u16* __restrict__ Qe)
{
    int tile = blockIdx.x, bh = blockIdx.y;
    int b = bh >> 3, hh = bh & 7;
    int tid = threadIdx.x, w = tid>>6, l = tid&63;
    int lg = l>>4, lc = l&15;
    int wr = (w>>1)*64, wc = (w&1)*64;
    int pi0 = tile*128;

    f32x4 acc[4][4];
    #pragma unroll
    for (int m = 0; m < 4; m++)
        #pragma unroll
        for (int n = 0; n < 4; n++) { f32x4 z = {0.f,0.f,0.f,0.f}; acc[m][n] = z; }

    s16x8 af[4][2];
    #pragma unroll
    for (int m = 0; m < 4; m++) {
        int pi = pi0 + wr + m*16 + lc;
        const u16* qp = q + ((size_t)(b*SS + NE + pi))*DIM + hh*HD + lg*8;
        af[m][0] = *(const s16x8*)qp;
        af[m][1] = *(const s16x8*)(qp + 32);
    }
    s16x8 bf[4][2];
    #pragma unroll
    for (int n = 0; n < 4; n++) {
        int tau = wc + n*16 + lc;
        const float* ep = (tau < 64) ? (x_emb + (size_t)tau*HD) : (y_emb + (size_t)(tau-64)*HD);
        #pragma unroll
        for (int ks = 0; ks < 2; ks++) {
            const float* e8 = ep + ks*32 + lg*8;
            s16x8 bv;
            #pragma unroll
            for (int t2 = 0; t2 < 8; t2++) bv[t2] = (short)f2b(e8[t2]);
            bf[n][ks] = bv;
        }
    }
    #pragma unroll
    for (int ks = 0; ks < 2; ks++)
        #pragma unroll
        for (int m = 0; m < 4; m++)
            #pragma unroll
            for (int n = 0; n < 4; n++)
                acc[m][n] = __builtin_amdgcn_mfma_f32_16x16x32_bf16(af[m][ks], bf[n][ks], acc[m][n], 0, 0, 0);

    #pragma unroll
    for (int m = 0; m < 4; m++) {
        #pragma unroll
        for (int r = 0; r < 4; r++) {
            int pi = pi0 + wr + m*16 + lg*4 + r;
            int ci = pi & 31, ri = pi >> 5;
            size_t rowbase = ((size_t)bh*SS + NE + pi)*KE;
            #pragma unroll
            for (int n = 0; n < 4; n++) {
                int tau = wc + n*16 + lc;
                float v = acc[m][n][r];
                if (tau < 64) {
                    int c = tau + ci - 32;
                    if (c >= 0 && c < 32) Qe[rowbase + 64 + c] = f2b(v);
                } else {
                    int c = (tau - 64) + ri - 32;
                    if (c >= 0 && c < 32) Qe[rowbase + 96 + c] = f2b(v);
                }
            }
        }
    }
}

// ---------------- flash-style MFMA attention, 128-key double tile per softmax ----------------
#define KT2 128
#define NKT2 9    // ceil(1028/128)
#define NQT 17
__global__ __launch_bounds__(256) void attn_mfma(
    const u16* __restrict__ Qe, const u16* __restrict__ Ke,
    const u16* __restrict__ v, u16* __restrict__ o)
{
    __shared__ __align__(16) u16 Kl[128*192];       // 128 rows x 384B (swizzled) = 48 KB
    __shared__ __align__(16) u16 Vt[2][64][72];     // V^T per 64-key half = 18 KB
    __shared__ __align__(16) u16 Pl[4][16][72];     // per-wave P = 9 KB
    // XCD grouping: nwg=1088 = 8*136; same-bh blocks land on one XCD (L2 reuse of Ke/V)
    int bid = blockIdx.x;
    int g = (bid & 7)*136 + (bid >> 3);
    int qt = g % NQT, bh = g / NQT;
    int b = bh >> 3, hh = bh & 7;
    int tid = threadIdx.x, w = tid>>6, l = tid&63;
    int lg = l>>4, lc = l&15;
    int i0w = qt*64 + w*16;
    const s16x8 zs = {0,0,0,0,0,0,0,0};

    s16x8 qa[5];
    {
        int qrow = i0w + lc; if (qrow > SS-1) qrow = SS-1;
        const u16* qp = Qe + ((size_t)bh*SS + qrow)*KE + lg*8;
        #pragma unroll
        for (int ks = 0; ks < 5; ks++) qa[ks] = *(const s16x8*)(qp + ks*32);
    }

    float m_[4] = {-1e30f, -1e30f, -1e30f, -1e30f};
    float l_[4] = {0.f, 0.f, 0.f, 0.f};
    f32x4 oacc[4];
    #pragma unroll
    for (int f = 0; f < 4; f++) { f32x4 z = {0.f,0.f,0.f,0.f}; oacc[f] = z; }

    int skey = tid & 63, sd0 = (tid >> 6) * 16;

    for (int kt2 = 0; kt2 < NKT2; kt2++) {
        int j0 = kt2 * KT2;
        // ---- stage K_ext 128 rows x 20 units, XOR swizzle ----
        #pragma unroll
        for (int p = 0; p < 10; p++) {
            int e = p*256 + tid;
            int row = e / 20, u = e - row*20;
            int j = j0 + row;
            s16x8 kv = zs;
            if (j < SS) kv = *(const s16x8*)(Ke + ((size_t)bh*SS + j)*KE + u*8);
            *(s16x8*)((char*)Kl + row*384 + ((u ^ (row&7)) << 4)) = kv;
        }
        // ---- stage V^T both halves ----
        #pragma unroll
        for (int hb = 0; hb < 2; hb++) {
            int key = j0 + hb*64 + skey;
            uint4 v0 = {0,0,0,0}, v1 = {0,0,0,0};
            if (key < SS) {
                const uint4* vp = (const uint4*)(v + ((size_t)(b*SS + key))*DIM + hh*HD + sd0);
                v0 = vp[0]; v1 = vp[1];
            }
            const u16* pv = (const u16*)&v0;
            #pragma unroll
            for (int jj = 0; jj < 8; jj++) Vt[hb][sd0 + jj][skey] = pv[jj];
            pv = (const u16*)&v1;
            #pragma unroll
            for (int jj = 0; jj < 8; jj++) Vt[hb][sd0 + 8 + jj][skey] = pv[jj];
        }
        __syncthreads();

        // ---- QK_ext^T over 128 keys: 8 key-frags x 5 k-steps ----
        f32x4 s[8];
        #pragma unroll
        for (int f = 0; f < 8; f++) { f32x4 z = {0.f,0.f,0.f,0.f}; s[f] = z; }
        #pragma unroll
        for (int ks = 0; ks < 5; ks++)
            #pragma unroll
            for (int f = 0; f < 8; f++) {
                int row = f*16 + lc;
                s16x8 kb2 = *(const s16x8*)((const char*)Kl + row*384 + ((((ks<<2)+lg) ^ (row&7)) << 4));
                s[f] = __builtin_amdgcn_mfma_f32_16x16x32_bf16(qa[ks], kb2, s[f], 0, 0, 0);
            }

        // ---- online softmax: ONE pass per 128 keys ----
        #pragma unroll
        for (int r = 0; r < 4; r++) {
            #pragma unroll
            for (int f = 0; f < 8; f++) {
                int j = j0 + f*16 + lc;
                if (j >= SS) s[f][r] = -1e30f;
            }
            float t4 = fmaxf(fmaxf(fmaxf(s[0][r], s[1][r]), fmaxf(s[2][r], s[3][r])),
                             fmaxf(fmaxf(s[4][r], s[5][r]), fmaxf(s[6][r], s[7][r])));
            t4 = fmaxf(t4, __shfl_xor(t4, 1));
            t4 = fmaxf(t4, __shfl_xor(t4, 2));
            t4 = fmaxf(t4, __shfl_xor(t4, 4));
            t4 = fmaxf(t4, __shfl_xor(t4, 8));
            float mn = fmaxf(m_[r], t4);
            float sc = __expf(m_[r] - mn);
            m_[r] = mn;
            float rs = 0.f;
            #pragma unroll
            for (int f = 0; f < 8; f++) {
                float p = __expf(s[f][r] - mn);
                s[f][r] = p;
                rs += p;
            }
            rs += __shfl_xor(rs, 1); rs += __shfl_xor(rs, 2);
            rs += __shfl_xor(rs, 4); rs += __shfl_xor(rs, 8);
            l_[r] = l_[r]*sc + rs;
            #pragma unroll
            for (int f = 0; f < 4; f++) oacc[f][r] *= sc;
        }
        // ---- P -> LDS (wave-private) + PV, per 64-key half ----
        #pragma unroll
        for (int hb = 0; hb < 2; hb++) {
            #pragma unroll
            for (int r = 0; r < 4; r++)
                #pragma unroll
                for (int f = 0; f < 4; f++)
                    Pl[w][lg*4 + r][f*16 + lc] = f2b(s[hb*4 + f][r]);
            #pragma unroll
            for (int ks = 0; ks < 2; ks++) {
                s16x8 pa = *(const s16x8*)&Pl[w][lc][ks*32 + lg*8];
                #pragma unroll
                for (int f = 0; f < 4; f++) {
                    s16x8 vb = *(const s16x8*)&Vt[hb][f*16 + lc][ks*32 + lg*8];
                    oacc[f] = __builtin_amdgcn_mfma_f32_16x16x32_bf16(pa, vb, oacc[f], 0, 0, 0);
                }
            }
        }
        __syncthreads();
    }
    #pragma unroll
    for (int r = 0; r < 4; r++) {
        int i = i0w + lg*4 + r;
        if (i >= SS) continue;
        float inv = 1.0f / l_[r];
        #pragma unroll
        for (int f = 0; f < 4; f++)
            o[((size_t)(b*SS + i))*DIM + hh*HD + f*16 + lc] = f2b(oacc[f][r] * inv);
    }
}

// ---------------- classifier ----------------
__global__ void cls_kernel(const float* __restrict__ h, const float* __restrict__ Wc,
                           const float* __restrict__ bc, float* __restrict__ out) {
    int g = blockIdx.x*4 + (threadIdx.x >> 6);
    int lane = threadIdx.x & 63;
    if (g >= BB*S2) return;
    int b = g >> 10, p = g & 1023;
    const float* hr = h + ((size_t)(b*SS + NE + p))*DIM;
    float a0 = 0.f, a1 = 0.f;
    for (int d = lane; d < DIM; d += 64) {
        float hv = hr[d];
        a0 += hv * Wc[d*NC + 0];
        a1 += hv * Wc[d*NC + 1];
    }
    for (int off = 32; off; off >>= 1) { a0 += __shfl_down(a0, off); a1 += __shfl_down(a1, off); }
    if (lane == 0) {
        out[((size_t)(b*NC + 0))*S2 + p] = a0 + bc[0];
        out[((size_t)(b*NC + 1))*S2 + p] = a1 + bc[1];
    }
}

extern "C" void kernel_launch(void* const* d_in, const int* in_sizes, int n_in,
                              void* d_out, int out_size, void* d_ws, size_t ws_size,
                              hipStream_t stream) {
    const float* x      = (const float*)d_in[0];
    const float* patches= (const float*)d_in[1];
    const float* We     = (const float*)d_in[2];
    const float* be     = (const float*)d_in[3];
    const float* x_emb  = (const float*)d_in[4];
    const float* y_emb  = (const float*)d_in[5];
    const float* pad0   = (const float*)d_in[6];
    const float* pad1   = (const float*)d_in[7];
    const float* Wq     = (const float*)d_in[8];
    const float* bq     = (const float*)d_in[9];
    const float* Wk     = (const float*)d_in[10];
    const float* bk     = (const float*)d_in[11];
    const float* Wv     = (const float*)d_in[12];
    const float* bv     = (const float*)d_in[13];
    const float* Wo     = (const float*)d_in[14];
    const float* bo     = (const float*)d_in[15];
    const float* ln1_g  = (const float*)d_in[16];
    const float* ln1_b  = (const float*)d_in[17];
    const float* ln2_g  = (const float*)d_in[18];
    const float* ln2_b  = (const float*)d_in[19];
    const float* W1     = (const float*)d_in[20];
    const float* b1     = (const float*)d_in[21];
    const float* W2     = (const float*)d_in[22];
    const float* b2     = (const float*)d_in[23];
    const float* Wc     = (const float*)d_in[24];
    const float* bc     = (const float*)d_in[25];
    float* out = (float*)d_out;

    float* ws = (float*)d_ws;
    const size_t MD = (size_t)MM*DIM;                  // 4,210,688
    float* h  = ws;                                    // MD f32
    u16* hn   = (u16*)(ws + MD);                       // MD bf16
    u16* qb   = (u16*)(ws + MD + MD/2);                // 4x MD bf16 (q,k,v,o); tb aliases
    u16* kb   = qb + MD;
    u16* vb   = qb + 2*MD;
    u16* ob   = qb + 3*MD;
    u16* tb   = qb;
    u16* Qe   = (u16*)(ws + 3*MD + MD/2);              // EXT u16
    u16* Ke   = Qe + EXT;                              // EXT u16
    float* after = ws + 3*MD + MD/2 + EXT;             // Qe+Ke = 2*EXT u16 = EXT floats
    float* qp0 = after;
    float* qp1 = qp0 + 65792;
    float* bqkv = qp1 + 65792;                         // 1536 f32
    u16* wt   = (u16*)(bqkv + 1536);                   // 6,291,456 u16

    const size_t WL = 3145728;   // per-layer transposed-weight block (u16)

    for (int l = 0; l < LL; l++) {
        u16* base = wt + (size_t)l*WL;
        transp_kernel<<<dim3(16,16), 256, 0, stream>>>(Wq + (size_t)l*DIM*DIM, base + 0,        DIM, DIM);
        transp_kernel<<<dim3(16,16), 256, 0, stream>>>(Wk + (size_t)l*DIM*DIM, base + 262144,   DIM, DIM);
        transp_kernel<<<dim3(16,16), 256, 0, stream>>>(Wv + (size_t)l*DIM*DIM, base + 524288,   DIM, DIM);
        transp_kernel<<<dim3(16,16), 256, 0, stream>>>(Wo + (size_t)l*DIM*DIM, base + 786432,   DIM, DIM);
        transp_kernel<<<dim3(64,16), 256, 0, stream>>>(W1 + (size_t)l*DIM*FFD, base + 1048576,  DIM, FFD);
        transp_kernel<<<dim3(16,64), 256, 0, stream>>>(W2 + (size_t)l*FFD*DIM, base + 2097152,  FFD, DIM);
    }

    embed_kernel<<<MM, 256, 0, stream>>>(x, patches, We, be, h);

    const int extUnits = (int)(EXT / 8);
    const int extBlocks = (extUnits + 255) / 256;

    for (int l = 0; l < LL; l++) {
        u16* base = wt + (size_t)l*WL;
        cat_bias_kernel<<<6, 256, 0, stream>>>(bq + (size_t)l*DIM, bk + (size_t)l*DIM, bv + (size_t)l*DIM, bqkv);
        ln_kernel<<<MM, 256, 0, stream>>>(h, hn, ln1_g + l*DIM, ln1_b + l*DIM);
        mfma_gemm<2,0><<<65*12, 256, 0, stream>>>(hn, base, bqkv, nullptr, nullptr, qb, kb, vb, MM, 1536, DIM, 12);
        qp_kernel<<<(BB*NH*SS + 255)/256, 256, 0, stream>>>(qb, pad0, pad1, qp0, qp1);
        qext_kernel<<<extBlocks, 256, 0, stream>>>(qb, qp0, qp1, Qe);
        qxy_mfma<<<dim3(8, BB*NH), 256, 0, stream>>>(qb, x_emb, y_emb, Qe);
        kext_kernel<<<extBlocks, 256, 0, stream>>>(kb, Ke);
        attn_mfma<<<NQT*BB*NH, 256, 0, stream>>>(Qe, Ke, vb, ob);
        mfma_gemm<0,0><<<65*4, 256, 0, stream>>>(ob, base + 786432, bo + (size_t)l*DIM, h, h, nullptr, nullptr, nullptr, MM, DIM, DIM, 4);
        ln_kernel<<<MM, 256, 0, stream>>>(h, hn, ln2_g + l*DIM, ln2_b + l*DIM);
        mfma_gemm<1,1><<<65*16, 256, 0, stream>>>(hn, base + 1048576, b1 + (size_t)l*FFD, nullptr, nullptr, tb, nullptr, nullptr, MM, FFD, DIM, 16);
        mfma_gemm<0,0><<<65*4, 256, 0, stream>>>(tb, base + 2097152, b2 + (size_t)l*DIM, h, h, nullptr, nullptr, nullptr, MM, DIM, FFD, 4);
    }

    cls_kernel<<<(BB*S2)/4, 256, 0, stream>>>(h, Wc, bc, out);
}

// Round 9
// 727.535 us; speedup vs baseline: 1.1824x; 1.1824x over previous
//
#include <hip/hip_runtime.h>
#include <hip/hip_bf16.h>

#define DS 32
#define DIM 512
#define NH 8
#define HD 64
#define NE 4
#define NC 2
#define BB 8
#define LL 2
#define FFD 2048
#define S2 1024
#define SS 1028
#define MM (BB*SS)          // 8224 rows
#define KE 160              // extended K dim for bias-folded attention
#define EXT ((size_t)BB*NH*SS*KE)

typedef __attribute__((ext_vector_type(8))) short s16x8;
typedef __attribute__((ext_vector_type(4))) float f32x4;
typedef unsigned short u16;

__device__ __forceinline__ u16 f2b(float f) {
    __hip_bfloat16 h = __float2bfloat16(f);
    return *reinterpret_cast<u16*>(&h);
}
__device__ __forceinline__ float b2f(u16 u) {
    __hip_bfloat16 h;
    *reinterpret_cast<u16*>(&h) = u;
    return __bfloat162float(h);
}

// async global->LDS 16B copy. LDS dest = wave-uniform base + lane*16.
__device__ __forceinline__ void gload_lds16(const void* g, void* l) {
    __builtin_amdgcn_global_load_lds(
        (const __attribute__((address_space(1))) void*)(uintptr_t)g,
        (__attribute__((address_space(3))) void*)(uint32_t)(uintptr_t)l,
        16, 0, 0);
}

// ---------------- embed ----------------
__global__ void embed_kernel(const float* __restrict__ x, const float* __restrict__ patches,
                             const float* __restrict__ We, const float* __restrict__ be,
                             float* __restrict__ h) {
    int row = blockIdx.x;
    int b = row / SS, i = row % SS;
    float* hr = h + (size_t)row * DIM;
    if (i < NE) {
        const float* xr = x + (size_t)b*NE*DIM + (size_t)i*DIM;
        for (int d = threadIdx.x; d < DIM; d += blockDim.x) hr[d] = xr[d];
    } else {
        int p = i - NE;
        float c0 = patches[(size_t)b*3*S2 + 0*S2 + p];
        float c1 = patches[(size_t)b*3*S2 + 1*S2 + p];
        float c2 = patches[(size_t)b*3*S2 + 2*S2 + p];
        for (int d = threadIdx.x; d < DIM; d += blockDim.x)
            hr[d] = be[d] + c0*We[d] + c1*We[DIM+d] + c2*We[2*DIM+d];
    }
}

// ---------------- layernorm: f32 in -> bf16 out ----------------
__global__ void ln_kernel(const float* __restrict__ in, u16* __restrict__ out,
                          const float* __restrict__ g, const float* __restrict__ bt) {
    int row = blockIdx.x;
    const float* xr = in + (size_t)row*DIM;
    int t = threadIdx.x;
    float v0 = xr[t], v1 = xr[t+256];
    float s = v0 + v1, s2 = v0*v0 + v1*v1;
    for (int off = 32; off; off >>= 1) { s += __shfl_down(s, off); s2 += __shfl_down(s2, off); }
    __shared__ float ps[4], ps2[4];
    int wid = t >> 6, lane = t & 63;
    if (lane == 0) { ps[wid] = s; ps2[wid] = s2; }
    __syncthreads();
    if (t == 0) { ps[0] = ps[0]+ps[1]+ps[2]+ps[3]; ps2[0] = ps2[0]+ps2[1]+ps2[2]+ps2[3]; }
    __syncthreads();
    float mean = ps[0] * (1.0f/DIM);
    float var  = ps2[0] * (1.0f/DIM) - mean*mean;
    float inv = rsqrtf(var + 1e-5f);
    u16* orow = out + (size_t)row*DIM;
    orow[t]     = f2b((v0 - mean)*inv*g[t]     + bt[t]);
    orow[t+256] = f2b((v1 - mean)*inv*g[t+256] + bt[t+256]);
}

// ---------------- transpose+convert: src f32 [R][C] -> dst bf16 [C][R] ----------------
__global__ void transp_kernel(const float* __restrict__ src, u16* __restrict__ dst,
                              int R, int C) {
    __shared__ float tile[32][33];
    int c0 = blockIdx.x*32, r0 = blockIdx.y*32;
    int tx = threadIdx.x & 31, ty = threadIdx.x >> 5;   // 32 x 8
    #pragma unroll
    for (int ii = 0; ii < 4; ii++)
        tile[ty + ii*8][tx] = src[(size_t)(r0 + ty + ii*8)*C + c0 + tx];
    __syncthreads();
    #pragma unroll
    for (int ii = 0; ii < 4; ii++)
        dst[(size_t)(c0 + ty + ii*8)*R + r0 + tx] = f2b(tile[tx][ty + ii*8]);
}

__global__ void cat_bias_kernel(const float* __restrict__ bq, const float* __restrict__ bk,
                                const float* __restrict__ bv, float* __restrict__ out) {
    int t = blockIdx.x*256 + threadIdx.x;
    if (t >= 1536) return;
    out[t] = (t < 512) ? bq[t] : (t < 1024 ? bk[t-512] : bv[t-1024]);
}

// ---------------- bf16 MFMA GEMM: gload_lds + LDS double-buffer 2-phase pipeline ----------------
// 1D grid with bijective XCD chunking (m204); Nt = N/128.
// MODE: 0 = f32 out + residual, 1 = bf16 out (RELU opt), 2 = qkv split (Cb=q, kd, vd)
template<int MODE, int RELU>
__global__ __launch_bounds__(256) void mfma_gemm(
    const u16* __restrict__ A, const u16* __restrict__ WT,
    const float* __restrict__ bias, const float* __restrict__ res,
    float* __restrict__ Cf, u16* __restrict__ Cb,
    u16* __restrict__ kd, u16* __restrict__ vd,
    int M, int N, int K, int Nt)
{
    __shared__ __align__(16) u16 a_lds[2][128*64];   // 2 x 16 KB
    __shared__ __align__(16) u16 b_lds[2][128*64];   // 2 x 16 KB
    int nwg = gridDim.x;
    int q8 = nwg >> 3, r8 = nwg & 7;
    int bid = blockIdx.x;
    int xcd = bid & 7, loc = bid >> 3;
    int g = (xcd < r8 ? xcd*(q8+1) : r8*(q8+1) + (xcd - r8)*q8) + loc;
    int row0 = (g / Nt) * 128, col0 = (g % Nt) * 128;

    int tid = threadIdx.x, w = tid>>6, l = tid&63;
    int lg = l>>4, lc = l&15;
    int wr = (w>>1)*64, wc = (w&1)*64;
    f32x4 acc[4][4];
    #pragma unroll
    for (int m = 0; m < 4; m++)
        #pragma unroll
        for (int n = 0; n < 4; n++) { f32x4 z = {0.f,0.f,0.f,0.f}; acc[m][n] = z; }

    int c16 = l & 7;
    auto STAGE = [&](int buf, int kk) {
        #pragma unroll
        for (int p = 0; p < 4; p++) {
            int e = p*256 + tid;           // 16B-unit index; linear LDS dest = 16*e bytes
            int r = e >> 3;
            int ra = row0 + r; if (ra > M-1) ra = M-1;
            gload_lds16(A  + (size_t)ra*K + kk + c16*8,          a_lds[buf] + p*2048 + w*512);
            gload_lds16(WT + (size_t)(col0 + r)*K + kk + c16*8,  b_lds[buf] + p*2048 + w*512);
        }
    };

    STAGE(0, 0);
    __syncthreads();                       // drain prologue loads
    int nk = K >> 6;
    for (int ki = 0; ki < nk; ki++) {
        int cur = ki & 1;
        if (ki + 1 < nk) STAGE(cur ^ 1, (ki + 1) << 6);   // async DMA flies during MFMA below
        #pragma unroll
        for (int ks = 0; ks < 2; ks++) {
            int cb = ks*32 + lg*8;
            s16x8 af[4], bfr[4];
            #pragma unroll
            for (int m = 0; m < 4; m++)
                af[m] = *(const s16x8*)(a_lds[cur] + (wr + m*16 + lc)*64 + cb);
            #pragma unroll
            for (int n = 0; n < 4; n++)
                bfr[n] = *(const s16x8*)(b_lds[cur] + (wc + n*16 + lc)*64 + cb);
            #pragma unroll
            for (int m = 0; m < 4; m++)
                #pragma unroll
                for (int n = 0; n < 4; n++)
                    acc[m][n] = __builtin_amdgcn_mfma_f32_16x16x32_bf16(af[m], bfr[n], acc[m][n], 0, 0, 0);
        }
        __syncthreads();                   // one barrier per k-step: drains next-tile loads
    }
    #pragma unroll
    for (int m = 0; m < 4; m++) {
        #pragma unroll
        for (int r = 0; r < 4; r++) {
            int row = row0 + wr + m*16 + lg*4 + r;
            if (row >= M) continue;
            #pragma unroll
            for (int n = 0; n < 4; n++) {
                int col = col0 + wc + n*16 + lc;
                float v = acc[m][n][r] + bias[col];
                if (MODE == 2) {
                    int which = col >> 9, c2 = col & 511;
                    if (which == 0) v *= 0.125f;
                    u16* dst = (which == 0) ? Cb : (which == 1 ? kd : vd);
                    dst[(size_t)row*512 + c2] = f2b(v);
                } else if (MODE == 1) {
                    if (RELU) v = fmaxf(v, 0.f);
                    Cb[(size_t)row*N + col] = f2b(v);
                } else {
                    Cf[(size_t)row*N + col] = v + res[(size_t)row*N + col];
                }
            }
        }
    }
}

// ---------------- qp: qp0/1[bh,i] = q[b,i,h,:]·pad0/1 (f32 out) ----------------
__global__ void qp_kernel(const u16* __restrict__ q, const float* __restrict__ pad0,
                          const float* __restrict__ pad1, float* __restrict__ qp0,
                          float* __restrict__ qp1) {
    int idx = blockIdx.x * blockDim.x + threadIdx.x;
    if (idx >= BB*NH*SS) return;
    int i = idx % SS; int bh = idx / SS; int b = bh >> 3, hh = bh & 7;
    const u16* qr = q + ((size_t)(b*SS + i))*DIM + hh*HD;
    float a0 = 0.f, a1 = 0.f;
    #pragma unroll 8
    for (int d = 0; d < HD; d++) { float qv = b2f(qr[d]); a0 += qv*pad0[d]; a1 += qv*pad1[d]; }
    qp0[idx] = a0; qp1[idx] = a1;
}

// ---------------- Q_ext skeleton (vectorized, 8 u16/thread) ----------------
__global__ void qext_kernel(const u16* __restrict__ qb, const float* __restrict__ qp0,
                            const float* __restrict__ qp1, u16* __restrict__ Qe) {
    size_t id = (size_t)blockIdx.x*256 + threadIdx.x;     // unit index (8 u16 each)
    if (id >= EXT/8) return;
    int u = (int)(id % 20);
    size_t row = id / 20;                                  // bh*SS + i
    int bh = (int)(row / SS), i = (int)(row - (size_t)bh*SS);
    int b = bh >> 3, hh = bh & 7;
    s16x8 val = {0,0,0,0,0,0,0,0};
    if (u < 8) {
        val = *(const s16x8*)(qb + ((size_t)(b*SS + i))*DIM + hh*HD + u*8);
    } else if (u == 16) {
        float v128 = (i < NE) ? qp0[bh*SS + i] : qp1[bh*SS + i];
        float v129 = (i < NE) ? qp1[bh*SS + i] : 0.f;
        val[0] = (short)f2b(v128);
        val[1] = (short)f2b(v129);
    }
    *(s16x8*)(Qe + row*KE + u*8) = val;
}

// ---------------- K_ext build (vectorized) ----------------
__global__ void kext_kernel(const u16* __restrict__ kb, u16* __restrict__ Ke) {
    size_t id = (size_t)blockIdx.x*256 + threadIdx.x;
    if (id >= EXT/8) return;
    int u = (int)(id % 20);
    size_t row = id / 20;
    int bh = (int)(row / SS), j = (int)(row - (size_t)bh*SS);
    int b = bh >> 3, hh = bh & 7;
    const short ONE = 0x3F80;
    s16x8 val = {0,0,0,0,0,0,0,0};
    if (u < 8) {
        val = *(const s16x8*)(kb + ((size_t)(b*SS + j))*DIM + hh*HD + u*8);
    } else {
        int pj = j - NE, cj = pj & 31, rj = pj >> 5;
        #pragma unroll
        for (int e = 0; e < 8; e++) {
            int t = u*8 + e;
            short v = 0;
            if (j >= NE) {
                if (t < 96)       { if (cj == t-64) v = ONE; }
                else if (t < 128) { if (rj == t-96) v = ONE; }
                else if (t == 129) v = ONE;
            } else if (t == 128) v = ONE;
            val[e] = v;
        }
    }
    *(s16x8*)(Ke + row*KE + u*8) = val;
}

// ---------------- qx/qy via MFMA, windows scattered directly into Q_ext ----------------
__global__ __launch_bounds__(256) void qxy_mfma(
    const u16* __restrict__ q, const float* __restrict__ x_emb,
    const float* __restrict__ y_emb, u16* __restrict__ Qe)
{
    int tile = blockIdx.x, bh = blockIdx.y;
    int b = bh >> 3, hh = bh & 7;
    int tid = threadIdx.x, w = tid>>6, l = tid&63;
    int lg = l>>4, lc = l&15;
    int wr = (w>>1)*64, wc = (w&1)*64;
    int pi0 = tile*128;

    f32x4 acc[4][4];
    #pragma unroll
    for (int m = 0; m < 4; m++)
        #pragma unroll
        for (int n = 0; n < 4; n++) { f32x4 z = {0.f,0.f,0.f,0.f}; acc[m][n] = z; }

    s16x8 af[4][2];
    #pragma unroll
    for (int m = 0; m < 4; m++) {
        int pi = pi0 + wr + m*16 + lc;
        const u16* qp = q + ((size_t)(b*SS + NE + pi))*DIM + hh*HD + lg*8;
        af[m][0] = *(const s16x8*)qp;
        af[m][1] = *(const s16x8*)(qp + 32);
    }
    s16x8 bf[4][2];
    #pragma unroll
    for (int n = 0; n < 4; n++) {
        int tau = wc + n*16 + lc;
        const float* ep = (tau < 64) ? (x_emb + (size_t)tau*HD) : (y_emb + (size_t)(tau-64)*HD);
        #pragma unroll
        for (int ks = 0; ks < 2; ks++) {
            const float* e8 = ep + ks*32 + lg*8;
            s16x8 bv;
            #pragma unroll
            for (int t2 = 0; t2 < 8; t2++) bv[t2] = (short)f2b(e8[t2]);
            bf[n][ks] = bv;
        }
    }
    #pragma unroll
    for (int ks = 0; ks < 2; ks++)
        #pragma unroll
        for (int m = 0; m < 4; m++)
            #pragma unroll
            for (int n = 0; n < 4; n++)
                acc[m][n] = __builtin_amdgcn_mfma_f32_16x16x32_bf16(af[m][ks], bf[n][ks], acc[m][n], 0, 0, 0);

    #pragma unroll
    for (int m = 0; m < 4; m++) {
        #pragma unroll
        for (int r = 0; r < 4; r++) {
            int pi = pi0 + wr + m*16 + lg*4 + r;
            int ci = pi & 31, ri = pi >> 5;
            size_t rowbase = ((size_t)bh*SS + NE + pi)*KE;
            #pragma unroll
            for (int n = 0; n < 4; n++) {
                int tau = wc + n*16 + lc;
                float v = acc[m][n][r];
                if (tau < 64) {
                    int c = tau + ci - 32;
                    if (c >= 0 && c < 32) Qe[rowbase + 64 + c] = f2b(v);
                } else {
                    int c = (tau - 64) + ri - 32;
                    if (c >= 0 && c < 32) Qe[rowbase + 96 + c] = f2b(v);
                }
            }
        }
    }
}

// ---------------- flash-style MFMA attention: 64-key tiles + XCD swizzle ----------------
#define KT 64
#define NKT 17
#define NQT 17
__global__ __launch_bounds__(256) void attn_mfma(
    const u16* __restrict__ Qe, const u16* __restrict__ Ke,
    const u16* __restrict__ v, u16* __restrict__ o)
{
    __shared__ __align__(16) u16 Kl[64*192];        // 64 rows x 384B (swizzled) = 24 KB
    __shared__ __align__(16) u16 Vt[64][72];        // V^T [d][key] = 9 KB
    __shared__ __align__(16) u16 Pl[4][16][72];     // per-wave P = 9 KB  (total 43 KB -> 3 blk/CU)
    // XCD grouping: nwg=1088 = 8*136; all 17 q-tiles of a bh co-resident per XCD (L2 reuse)
    int bid = blockIdx.x;
    int g = (bid & 7)*136 + (bid >> 3);
    int qt = g % NQT, bh = g / NQT;
    int b = bh >> 3, hh = bh & 7;
    int tid = threadIdx.x, w = tid>>6, l = tid&63;
    int lg = l>>4, lc = l&15;
    int i0w = qt*64 + w*16;
    const s16x8 zs = {0,0,0,0,0,0,0,0};

    s16x8 qa[5];
    {
        int qrow = i0w + lc; if (qrow > SS-1) qrow = SS-1;
        const u16* qp = Qe + ((size_t)bh*SS + qrow)*KE + lg*8;
        #pragma unroll
        for (int ks = 0; ks < 5; ks++) qa[ks] = *(const s16x8*)(qp + ks*32);
    }

    float m_[4] = {-1e30f, -1e30f, -1e30f, -1e30f};
    float l_[4] = {0.f, 0.f, 0.f, 0.f};
    f32x4 oacc[4];
    #pragma unroll
    for (int f = 0; f < 4; f++) { f32x4 z = {0.f,0.f,0.f,0.f}; oacc[f] = z; }

    int skey = tid & 63, sd0 = (tid >> 6) * 16;

    for (int kt2 = 0; kt2 < NKT; kt2++) {
        int j0 = kt2 * KT;
        // ---- stage K_ext tile: 64 rows x 20 units, XOR swizzle ----
        #pragma unroll
        for (int p = 0; p < 5; p++) {
            int e = p*256 + tid;
            int row = e / 20, u = e - row*20;
            int j = j0 + row;
            s16x8 kv = zs;
            if (j < SS) kv = *(const s16x8*)(Ke + ((size_t)bh*SS + j)*KE + u*8);
            *(s16x8*)((char*)Kl + row*384 + ((u ^ (row&7)) << 4)) = kv;
        }
        // ---- stage V^T ----
        {
            int key = j0 + skey;
            uint4 v0 = {0,0,0,0}, v1 = {0,0,0,0};
            if (key < SS) {
                const uint4* vp = (const uint4*)(v + ((size_t)(b*SS + key))*DIM + hh*HD + sd0);
                v0 = vp[0]; v1 = vp[1];
            }
            const u16* pv = (const u16*)&v0;
            #pragma unroll
            for (int jj = 0; jj < 8; jj++) Vt[sd0 + jj][skey] = pv[jj];
            pv = (const u16*)&v1;
            #pragma unroll
            for (int jj = 0; jj < 8; jj++) Vt[sd0 + 8 + jj][skey] = pv[jj];
        }
        __syncthreads();

        // ---- QK_ext^T: 5 k-steps x 4 key-frags ----
        f32x4 s[4];
        #pragma unroll
        for (int f = 0; f < 4; f++) { f32x4 z = {0.f,0.f,0.f,0.f}; s[f] = z; }
        #pragma unroll
        for (int ks = 0; ks < 5; ks++)
            #pragma unroll
            for (int f = 0; f < 4; f++) {
                int row = f*16 + lc;
                s16x8 kb2 = *(const s16x8*)((const char*)Kl + row*384 + ((((ks<<2)+lg) ^ (row&7)) << 4));
                s[f] = __builtin_amdgcn_mfma_f32_16x16x32_bf16(qa[ks], kb2, s[f], 0, 0, 0);
            }

        // ---- online softmax ----
        #pragma unroll
        for (int r = 0; r < 4; r++) {
            #pragma unroll
            for (int f = 0; f < 4; f++) {
                int j = j0 + f*16 + lc;
                if (j >= SS) s[f][r] = -1e30f;
            }
            float t4 = fmaxf(fmaxf(s[0][r], s[1][r]), fmaxf(s[2][r], s[3][r]));
            t4 = fmaxf(t4, __shfl_xor(t4, 1));
            t4 = fmaxf(t4, __shfl_xor(t4, 2));
            t4 = fmaxf(t4, __shfl_xor(t4, 4));
            t4 = fmaxf(t4, __shfl_xor(t4, 8));
            float mn = fmaxf(m_[r], t4);
            float sc = __expf(m_[r] - mn);
            m_[r] = mn;
            float rs = 0.f;
            #pragma unroll
            for (int f = 0; f < 4; f++) {
                float p = __expf(s[f][r] - mn);
                s[f][r] = p;
                rs += p;
            }
            rs += __shfl_xor(rs, 1); rs += __shfl_xor(rs, 2);
            rs += __shfl_xor(rs, 4); rs += __shfl_xor(rs, 8);
            l_[r] = l_[r]*sc + rs;
            #pragma unroll
            for (int f = 0; f < 4; f++) oacc[f][r] *= sc;
        }
        // ---- P -> LDS (wave-private), then PV ----
        #pragma unroll
        for (int r = 0; r < 4; r++)
            #pragma unroll
            for (int f = 0; f < 4; f++)
                Pl[w][lg*4 + r][f*16 + lc] = f2b(s[f][r]);
        #pragma unroll
        for (int ks = 0; ks < 2; ks++) {
            s16x8 pa = *(const s16x8*)&Pl[w][lc][ks*32 + lg*8];
            #pragma unroll
            for (int f = 0; f < 4; f++) {
                s16x8 vb = *(const s16x8*)&Vt[f*16 + lc][ks*32 + lg*8];
                oacc[f] = __builtin_amdgcn_mfma_f32_16x16x32_bf16(pa, vb, oacc[f], 0, 0, 0);
            }
        }
        __syncthreads();
    }
    #pragma unroll
    for (int r = 0; r < 4; r++) {
        int i = i0w + lg*4 + r;
        if (i >= SS) continue;
        float inv = 1.0f / l_[r];
        #pragma unroll
        for (int f = 0; f < 4; f++)
            o[((size_t)(b*SS + i))*DIM + hh*HD + f*16 + lc] = f2b(oacc[f][r] * inv);
    }
}

// ---------------- classifier ----------------
__global__ void cls_kernel(const float* __restrict__ h, const float* __restrict__ Wc,
                           const float* __restrict__ bc, float* __restrict__ out) {
    int g = blockIdx.x*4 + (threadIdx.x >> 6);
    int lane = threadIdx.x & 63;
    if (g >= BB*S2) return;
    int b = g >> 10, p = g & 1023;
    const float* hr = h + ((size_t)(b*SS + NE + p))*DIM;
    float a0 = 0.f, a1 = 0.f;
    for (int d = lane; d < DIM; d += 64) {
        float hv = hr[d];
        a0 += hv * Wc[d*NC + 0];
        a1 += hv * Wc[d*NC + 1];
    }
    for (int off = 32; off; off >>= 1) { a0 += __shfl_down(a0, off); a1 += __shfl_down(a1, off); }
    if (lane == 0) {
        out[((size_t)(b*NC + 0))*S2 + p] = a0 + bc[0];
        out[((size_t)(b*NC + 1))*S2 + p] = a1 + bc[1];
    }
}

extern "C" void kernel_launch(void* const* d_in, const int* in_sizes, int n_in,
                              void* d_out, int out_size, void* d_ws, size_t ws_size,
                              hipStream_t stream) {
    const float* x      = (const float*)d_in[0];
    const float* patches= (const float*)d_in[1];
    const float* We     = (const float*)d_in[2];
    const float* be     = (const float*)d_in[3];
    const float* x_emb  = (const float*)d_in[4];
    const float* y_emb  = (const float*)d_in[5];
    const float* pad0   = (const float*)d_in[6];
    const float* pad1   = (const float*)d_in[7];
    const float* Wq     = (const float*)d_in[8];
    const float* bq     = (const float*)d_in[9];
    const float* Wk     = (const float*)d_in[10];
    const float* bk     = (const float*)d_in[11];
    const float* Wv     = (const float*)d_in[12];
    const float* bv     = (const float*)d_in[13];
    const float* Wo     = (const float*)d_in[14];
    const float* bo     = (const float*)d_in[15];
    const float* ln1_g  = (const float*)d_in[16];
    const float* ln1_b  = (const float*)d_in[17];
    const float* ln2_g  = (const float*)d_in[18];
    const float* ln2_b  = (const float*)d_in[19];
    const float* W1     = (const float*)d_in[20];
    const float* b1     = (const float*)d_in[21];
    const float* W2     = (const float*)d_in[22];
    const float* b2     = (const float*)d_in[23];
    const float* Wc     = (const float*)d_in[24];
    const float* bc     = (const float*)d_in[25];
    float* out = (float*)d_out;

    float* ws = (float*)d_ws;
    const size_t MD = (size_t)MM*DIM;                  // 4,210,688
    float* h  = ws;                                    // MD f32
    u16* hn   = (u16*)(ws + MD);                       // MD bf16
    u16* qb   = (u16*)(ws + MD + MD/2);                // 4x MD bf16 (q,k,v,o); tb aliases
    u16* kb   = qb + MD;
    u16* vb   = qb + 2*MD;
    u16* ob   = qb + 3*MD;
    u16* tb   = qb;
    u16* Qe   = (u16*)(ws + 3*MD + MD/2);              // EXT u16
    u16* Ke   = Qe + EXT;                              // EXT u16
    float* after = ws + 3*MD + MD/2 + EXT;             // Qe+Ke = 2*EXT u16 = EXT floats
    float* qp0 = after;
    float* qp1 = qp0 + 65792;
    float* bqkv = qp1 + 65792;                         // 1536 f32
    u16* wt   = (u16*)(bqkv + 1536);                   // 6,291,456 u16

    const size_t WL = 3145728;   // per-layer transposed-weight block (u16)

    for (int l = 0; l < LL; l++) {
        u16* base = wt + (size_t)l*WL;
        transp_kernel<<<dim3(16,16), 256, 0, stream>>>(Wq + (size_t)l*DIM*DIM, base + 0,        DIM, DIM);
        transp_kernel<<<dim3(16,16), 256, 0, stream>>>(Wk + (size_t)l*DIM*DIM, base + 262144,   DIM, DIM);
        transp_kernel<<<dim3(16,16), 256, 0, stream>>>(Wv + (size_t)l*DIM*DIM, base + 524288,   DIM, DIM);
        transp_kernel<<<dim3(16,16), 256, 0, stream>>>(Wo + (size_t)l*DIM*DIM, base + 786432,   DIM, DIM);
        transp_kernel<<<dim3(64,16), 256, 0, stream>>>(W1 + (size_t)l*DIM*FFD, base + 1048576,  DIM, FFD);
        transp_kernel<<<dim3(16,64), 256, 0, stream>>>(W2 + (size_t)l*FFD*DIM, base + 2097152,  FFD, DIM);
    }

    embed_kernel<<<MM, 256, 0, stream>>>(x, patches, We, be, h);

    const int extUnits = (int)(EXT / 8);
    const int extBlocks = (extUnits + 255) / 256;

    for (int l = 0; l < LL; l++) {
        u16* base = wt + (size_t)l*WL;
        cat_bias_kernel<<<6, 256, 0, stream>>>(bq + (size_t)l*DIM, bk + (size_t)l*DIM, bv + (size_t)l*DIM, bqkv);
        ln_kernel<<<MM, 256, 0, stream>>>(h, hn, ln1_g + l*DIM, ln1_b + l*DIM);
        mfma_gemm<2,0><<<65*12, 256, 0, stream>>>(hn, base, bqkv, nullptr, nullptr, qb, kb, vb, MM, 1536, DIM, 12);
        qp_kernel<<<(BB*NH*SS + 255)/256, 256, 0, stream>>>(qb, pad0, pad1, qp0, qp1);
        qext_kernel<<<extBlocks, 256, 0, stream>>>(qb, qp0, qp1, Qe);
        qxy_mfma<<<dim3(8, BB*NH), 256, 0, stream>>>(qb, x_emb, y_emb, Qe);
        kext_kernel<<<extBlocks, 256, 0, stream>>>(kb, Ke);
        attn_mfma<<<NQT*BB*NH, 256, 0, stream>>>(Qe, Ke, vb, ob);
        mfma_gemm<0,0><<<65*4, 256, 0, stream>>>(ob, base + 786432, bo + (size_t)l*DIM, h, h, nullptr, nullptr, nullptr, MM, DIM, DIM, 4);
        ln_kernel<<<MM, 256, 0, stream>>>(h, hn, ln2_g + l*DIM, ln2_b + l*DIM);
        mfma_gemm<1,1><<<65*16, 256, 0, stream>>>(hn, base + 1048576, b1 + (size_t)l*FFD, nullptr, nullptr, tb, nullptr, nullptr, MM, FFD, DIM, 16);
        mfma_gemm<0,0><<<65*4, 256, 0, stream>>>(tb, base + 2097152, b2 + (size_t)l*DIM, h, h, nullptr, nullptr, nullptr, MM, DIM, FFD, 4);
    }

    cls_kernel<<<(BB*S2)/4, 256, 0, stream>>>(h, Wc, bc, out);
}

// Round 11
// 702.200 us; speedup vs baseline: 1.2251x; 1.0361x over previous
//
#include <hip/hip_runtime.h>
#include <hip/hip_bf16.h>

#define DS 32
#define DIM 512
#define NH 8
#define HD 64
#define NE 4
#define NC 2
#define BB 8
#define LL 2
#define FFD 2048
#define S2 1024
#define SS 1028
#define MM (BB*SS)          // 8224 rows
#define KE 160              // extended K dim for bias-folded attention
#define EXT ((size_t)BB*NH*SS*KE)
#define WLD 3145728         // per-layer transposed-weight block (u16)

typedef __attribute__((ext_vector_type(8))) short s16x8;
typedef __attribute__((ext_vector_type(4))) float f32x4;
typedef unsigned short u16;

__device__ __forceinline__ u16 f2b(float f) {
    __hip_bfloat16 h = __float2bfloat16(f);
    return *reinterpret_cast<u16*>(&h);
}
__device__ __forceinline__ float b2f(u16 u) {
    __hip_bfloat16 h;
    *reinterpret_cast<u16*>(&h) = u;
    return __bfloat162float(h);
}

// async global->LDS 16B copy. LDS dest = wave-uniform base + lane*16.
__device__ __forceinline__ void gload_lds16(const void* g, void* l) {
    __builtin_amdgcn_global_load_lds(
        (const __attribute__((address_space(1))) void*)(uintptr_t)g,
        (__attribute__((address_space(3))) void*)(uint32_t)(uintptr_t)l,
        16, 0, 0);
}

// ---------------- embed ----------------
__global__ void embed_kernel(const float* __restrict__ x, const float* __restrict__ patches,
                             const float* __restrict__ We, const float* __restrict__ be,
                             float* __restrict__ h) {
    int row = blockIdx.x;
    int b = row / SS, i = row % SS;
    float* hr = h + (size_t)row * DIM;
    if (i < NE) {
        const float* xr = x + (size_t)b*NE*DIM + (size_t)i*DIM;
        for (int d = threadIdx.x; d < DIM; d += blockDim.x) hr[d] = xr[d];
    } else {
        int p = i - NE;
        float c0 = patches[(size_t)b*3*S2 + 0*S2 + p];
        float c1 = patches[(size_t)b*3*S2 + 1*S2 + p];
        float c2 = patches[(size_t)b*3*S2 + 2*S2 + p];
        for (int d = threadIdx.x; d < DIM; d += blockDim.x)
            hr[d] = be[d] + c0*We[d] + c1*We[DIM+d] + c2*We[2*DIM+d];
    }
}

// ---------------- layernorm: f32 in -> bf16 out ----------------
__global__ void ln_kernel(const float* __restrict__ in, u16* __restrict__ out,
                          const float* __restrict__ g, const float* __restrict__ bt) {
    int row = blockIdx.x;
    const float* xr = in + (size_t)row*DIM;
    int t = threadIdx.x;
    float v0 = xr[t], v1 = xr[t+256];
    float s = v0 + v1, s2 = v0*v0 + v1*v1;
    for (int off = 32; off; off >>= 1) { s += __shfl_down(s, off); s2 += __shfl_down(s2, off); }
    __shared__ float ps[4], ps2[4];
    int wid = t >> 6, lane = t & 63;
    if (lane == 0) { ps[wid] = s; ps2[wid] = s2; }
    __syncthreads();
    if (t == 0) { ps[0] = ps[0]+ps[1]+ps[2]+ps[3]; ps2[0] = ps2[0]+ps2[1]+ps2[2]+ps2[3]; }
    __syncthreads();
    float mean = ps[0] * (1.0f/DIM);
    float var  = ps2[0] * (1.0f/DIM) - mean*mean;
    float inv = rsqrtf(var + 1e-5f);
    u16* orow = out + (size_t)row*DIM;
    orow[t]     = f2b((v0 - mean)*inv*g[t]     + bt[t]);
    orow[t+256] = f2b((v1 - mean)*inv*g[t+256] + bt[t+256]);
}

// ---------------- batched transpose+convert: all 6 weights x both layers, one dispatch ----------------
// grid (1024, 6, LL); dst bf16 [C][R] from src f32 [R][C]
__global__ void transp_all(const float* __restrict__ Wq, const float* __restrict__ Wk,
                           const float* __restrict__ Wv, const float* __restrict__ Wo,
                           const float* __restrict__ W1, const float* __restrict__ W2,
                           u16* __restrict__ wt) {
    int widx = blockIdx.y, l = blockIdx.z;
    const float* src; u16* dst; int R, C;
    u16* base = wt + (size_t)l*WLD;
    if      (widx == 0) { src = Wq + (size_t)l*DIM*DIM; dst = base + 0;       R = DIM; C = DIM; }
    else if (widx == 1) { src = Wk + (size_t)l*DIM*DIM; dst = base + 262144;  R = DIM; C = DIM; }
    else if (widx == 2) { src = Wv + (size_t)l*DIM*DIM; dst = base + 524288;  R = DIM; C = DIM; }
    else if (widx == 3) { src = Wo + (size_t)l*DIM*DIM; dst = base + 786432;  R = DIM; C = DIM; }
    else if (widx == 4) { src = W1 + (size_t)l*DIM*FFD; dst = base + 1048576; R = DIM; C = FFD; }
    else                { src = W2 + (size_t)l*FFD*DIM; dst = base + 2097152; R = FFD; C = DIM; }
    int tilesC = C >> 5;
    int tile = blockIdx.x;
    if (tile >= tilesC * (R >> 5)) return;
    int c0 = (tile % tilesC) * 32, r0 = (tile / tilesC) * 32;
    __shared__ float t_[32][33];
    int tx = threadIdx.x & 31, ty = threadIdx.x >> 5;   // 32 x 8
    #pragma unroll
    for (int ii = 0; ii < 4; ii++)
        t_[ty + ii*8][tx] = src[(size_t)(r0 + ty + ii*8)*C + c0 + tx];
    __syncthreads();
    #pragma unroll
    for (int ii = 0; ii < 4; ii++)
        dst[(size_t)(c0 + ty + ii*8)*R + r0 + tx] = f2b(t_[tx][ty + ii*8]);
}

__global__ void cat_bias_kernel(const float* __restrict__ bq, const float* __restrict__ bk,
                                const float* __restrict__ bv, float* __restrict__ out) {
    int t = blockIdx.x*256 + threadIdx.x;
    if (t >= 1536) return;
    out[t] = (t < 512) ? bq[t] : (t < 1024 ? bk[t-512] : bv[t-1024]);
}

// ---------------- bf16 MFMA GEMM 128x128: gload_lds + LDS double-buffer ----------------
// MODE: 0 = f32 out + residual, 1 = bf16 out (RELU opt), 2 = qkv split (Cb=q, kd, vd)
template<int MODE, int RELU>
__global__ __launch_bounds__(256) void mfma_gemm(
    const u16* __restrict__ A, const u16* __restrict__ WT,
    const float* __restrict__ bias, const float* __restrict__ res,
    float* __restrict__ Cf, u16* __restrict__ Cb,
    u16* __restrict__ kd, u16* __restrict__ vd,
    int M, int N, int K, int Nt)
{
    __shared__ __align__(16) u16 a_lds[2][128*64];
    __shared__ __align__(16) u16 b_lds[2][128*64];
    int nwg = gridDim.x;
    int q8 = nwg >> 3, r8 = nwg & 7;
    int bid = blockIdx.x;
    int xcd = bid & 7, loc = bid >> 3;
    int g = (xcd < r8 ? xcd*(q8+1) : r8*(q8+1) + (xcd - r8)*q8) + loc;
    int row0 = (g / Nt) * 128, col0 = (g % Nt) * 128;

    int tid = threadIdx.x, w = tid>>6, l = tid&63;
    int lg = l>>4, lc = l&15;
    int wr = (w>>1)*64, wc = (w&1)*64;
    f32x4 acc[4][4];
    #pragma unroll
    for (int m = 0; m < 4; m++)
        #pragma unroll
        for (int n = 0; n < 4; n++) { f32x4 z = {0.f,0.f,0.f,0.f}; acc[m][n] = z; }

    int c16 = l & 7;
    auto STAGE = [&](int buf, int kk) {
        #pragma unroll
        for (int p = 0; p < 4; p++) {
            int e = p*256 + tid;
            int r = e >> 3;
            int ra = row0 + r; if (ra > M-1) ra = M-1;
            gload_lds16(A  + (size_t)ra*K + kk + c16*8,          a_lds[buf] + p*2048 + w*512);
            gload_lds16(WT + (size_t)(col0 + r)*K + kk + c16*8,  b_lds[buf] + p*2048 + w*512);
        }
    };

    STAGE(0, 0);
    __syncthreads();
    int nk = K >> 6;
    for (int ki = 0; ki < nk; ki++) {
        int cur = ki & 1;
        if (ki + 1 < nk) STAGE(cur ^ 1, (ki + 1) << 6);
        #pragma unroll
        for (int ks = 0; ks < 2; ks++) {
            int cb = ks*32 + lg*8;
            s16x8 af[4], bfr[4];
            #pragma unroll
            for (int m = 0; m < 4; m++)
                af[m] = *(const s16x8*)(a_lds[cur] + (wr + m*16 + lc)*64 + cb);
            #pragma unroll
            for (int n = 0; n < 4; n++)
                bfr[n] = *(const s16x8*)(b_lds[cur] + (wc + n*16 + lc)*64 + cb);
            #pragma unroll
            for (int m = 0; m < 4; m++)
                #pragma unroll
                for (int n = 0; n < 4; n++)
                    acc[m][n] = __builtin_amdgcn_mfma_f32_16x16x32_bf16(af[m], bfr[n], acc[m][n], 0, 0, 0);
        }
        __syncthreads();
    }
    #pragma unroll
    for (int m = 0; m < 4; m++) {
        #pragma unroll
        for (int r = 0; r < 4; r++) {
            int row = row0 + wr + m*16 + lg*4 + r;
            if (row >= M) continue;
            #pragma unroll
            for (int n = 0; n < 4; n++) {
                int col = col0 + wc + n*16 + lc;
                float v = acc[m][n][r] + bias[col];
                if (MODE == 2) {
                    int which = col >> 9, c2 = col & 511;
                    if (which == 0) v *= 0.125f;
                    u16* dst = (which == 0) ? Cb : (which == 1 ? kd : vd);
                    dst[(size_t)row*512 + c2] = f2b(v);
                } else if (MODE == 1) {
                    if (RELU) v = fmaxf(v, 0.f);
                    Cb[(size_t)row*N + col] = f2b(v);
                } else {
                    Cf[(size_t)row*N + col] = v + res[(size_t)row*N + col];
                }
            }
        }
    }
}

// ---------------- bf16 MFMA GEMM 64x128 (for N=512 shapes): 2x the grid, 3 blk/CU ----------------
// f32 out + residual only. Waves 2x2, each 32x64 (acc[2][4]).
__global__ __launch_bounds__(256) void mfma_gemm_n(
    const u16* __restrict__ A, const u16* __restrict__ WT,
    const float* __restrict__ bias, const float* __restrict__ res,
    float* __restrict__ Cf, int M, int N, int K, int Nt)
{
    __shared__ __align__(16) u16 a_lds[2][64*64];    // 2 x 8 KB
    __shared__ __align__(16) u16 b_lds[2][128*64];   // 2 x 16 KB
    int nwg = gridDim.x;
    int q8 = nwg >> 3, r8 = nwg & 7;
    int bid = blockIdx.x;
    int xcd = bid & 7, loc = bid >> 3;
    int g = (xcd < r8 ? xcd*(q8+1) : r8*(q8+1) + (xcd - r8)*q8) + loc;
    int row0 = (g / Nt) * 64, col0 = (g % Nt) * 128;

    int tid = threadIdx.x, w = tid>>6, l = tid&63;
    int lg = l>>4, lc = l&15;
    int wr = (w>>1)*32, wc = (w&1)*64;
    f32x4 acc[2][4];
    #pragma unroll
    for (int m = 0; m < 2; m++)
        #pragma unroll
        for (int n = 0; n < 4; n++) { f32x4 z = {0.f,0.f,0.f,0.f}; acc[m][n] = z; }

    int c16 = l & 7;
    auto STAGE = [&](int buf, int kk) {
        #pragma unroll
        for (int p = 0; p < 2; p++) {       // A: 64 rows x 8 units = 512 units
            int e = p*256 + tid;
            int r = e >> 3;
            int ra = row0 + r; if (ra > M-1) ra = M-1;
            gload_lds16(A + (size_t)ra*K + kk + c16*8, a_lds[buf] + p*2048 + w*512);
        }
        #pragma unroll
        for (int p = 0; p < 4; p++) {       // B: 128 rows x 8 units = 1024 units
            int e = p*256 + tid;
            int r = e >> 3;
            gload_lds16(WT + (size_t)(col0 + r)*K + kk + c16*8, b_lds[buf] + p*2048 + w*512);
        }
    };

    STAGE(0, 0);
    __syncthreads();
    int nk = K >> 6;
    for (int ki = 0; ki < nk; ki++) {
        int cur = ki & 1;
        if (ki + 1 < nk) STAGE(cur ^ 1, (ki + 1) << 6);
        #pragma unroll
        for (int ks = 0; ks < 2; ks++) {
            int cb = ks*32 + lg*8;
            s16x8 af[2], bfr[4];
            #pragma unroll
            for (int m = 0; m < 2; m++)
                af[m] = *(const s16x8*)(a_lds[cur] + (wr + m*16 + lc)*64 + cb);
            #pragma unroll
            for (int n = 0; n < 4; n++)
                bfr[n] = *(const s16x8*)(b_lds[cur] + (wc + n*16 + lc)*64 + cb);
            #pragma unroll
            for (int m = 0; m < 2; m++)
                #pragma unroll
                for (int n = 0; n < 4; n++)
                    acc[m][n] = __builtin_amdgcn_mfma_f32_16x16x32_bf16(af[m], bfr[n], acc[m][n], 0, 0, 0);
        }
        __syncthreads();
    }
    #pragma unroll
    for (int m = 0; m < 2; m++) {
        #pragma unroll
        for (int r = 0; r < 4; r++) {
            int row = row0 + wr + m*16 + lg*4 + r;
            if (row >= M) continue;
            #pragma unroll
            for (int n = 0; n < 4; n++) {
                int col = col0 + wc + n*16 + lc;
                size_t idx = (size_t)row*N + col;
                Cf[idx] = acc[m][n][r] + bias[col] + res[idx];
            }
        }
    }
}

// ---------------- qp: qp0/1[bh,i] = q[b,i,h,:]·pad0/1 (f32 out) ----------------
__global__ void qp_kernel(const u16* __restrict__ q, const float* __restrict__ pad0,
                          const float* __restrict__ pad1, float* __restrict__ qp0,
                          float* __restrict__ qp1) {
    int idx = blockIdx.x * blockDim.x + threadIdx.x;
    if (idx >= BB*NH*SS) return;
    int i = idx % SS; int bh = idx / SS; int b = bh >> 3, hh = bh & 7;
    const u16* qr = q + ((size_t)(b*SS + i))*DIM + hh*HD;
    float a0 = 0.f, a1 = 0.f;
    #pragma unroll 8
    for (int d = 0; d < HD; d++) { float qv = b2f(qr[d]); a0 += qv*pad0[d]; a1 += qv*pad1[d]; }
    qp0[idx] = a0; qp1[idx] = a1;
}

// ---------------- Q_ext skeleton (vectorized, 8 u16/thread) ----------------
__global__ void qext_kernel(const u16* __restrict__ qb, const float* __restrict__ qp0,
                            const float* __restrict__ qp1, u16* __restrict__ Qe) {
    size_t id = (size_t)blockIdx.x*256 + threadIdx.x;     // unit index (8 u16 each)
    if (id >= EXT/8) return;
    int u = (int)(id % 20);
    size_t row = id / 20;                                  // bh*SS + i
    int bh = (int)(row / SS), i = (int)(row - (size_t)bh*SS);
    int b = bh >> 3, hh = bh & 7;
    s16x8 val = {0,0,0,0,0,0,0,0};
    if (u < 8) {
        val = *(const s16x8*)(qb + ((size_t)(b*SS + i))*DIM + hh*HD + u*8);
    } else if (u == 16) {
        float v128 = (i < NE) ? qp0[bh*SS + i] : qp1[bh*SS + i];
        float v129 = (i < NE) ? qp1[bh*SS + i] : 0.f;
        val[0] = (short)f2b(v128);
        val[1] = (short)f2b(v129);
    }
    *(s16x8*)(Qe + row*KE + u*8) = val;
}

// ---------------- K_ext build (vectorized) ----------------
__global__ void kext_kernel(const u16* __restrict__ kb, u16* __restrict__ Ke) {
    size_t id = (size_t)blockIdx.x*256 + threadIdx.x;
    if (id >= EXT/8) return;
    int u = (int)(id % 20);
    size_t row = id / 20;
    int bh = (int)(row / SS), j = (int)(row - (size_t)bh*SS);
    int b = bh >> 3, hh = bh & 7;
    const short ONE = 0x3F80;
    s16x8 val = {0,0,0,0,0,0,0,0};
    if (u < 8) {
        val = *(const s16x8*)(kb + ((size_t)(b*SS + j))*DIM + hh*HD + u*8);
    } else {
        int pj = j - NE, cj = pj & 31, rj = pj >> 5;
        #pragma unroll
        for (int e = 0; e < 8; e++) {
            int t = u*8 + e;
            short v = 0;
            if (j >= NE) {
                if (t < 96)       { if (cj == t-64) v = ONE; }
                else if (t < 128) { if (rj == t-96) v = ONE; }
                else if (t == 129) v = ONE;
            } else if (t == 128) v = ONE;
            val[e] = v;
        }
    }
    *(s16x8*)(Ke + row*KE + u*8) = val;
}

// ---------------- qx/qy via MFMA, windows scattered directly into Q_ext ----------------
__global__ __launch_bounds__(256) void qxy_mfma(
    const u16* __restrict__ q, const float* __restrict__ x_emb,
    const float* __restrict__ y_emb, u16* __restrict__ Qe)
{
    int tile = blockIdx.x, bh = blockIdx.y;
    int b = bh >> 3, hh = bh & 7;
    int tid = threadIdx.x, w = tid>>6, l = tid&63;
    int lg = l>>4, lc = l&15;
    int wr = (w>>1)*64, wc = (w&1)*64;
    int pi0 = tile*128;

    f32x4 acc[4][4];
    #pragma unroll
    for (int m = 0; m < 4; m++)
        #pragma unroll
        for (int n = 0; n < 4; n++) { f32x4 z = {0.f,0.f,0.f,0.f}; acc[m][n] = z; }

    s16x8 af[4][2];
    #pragma unroll
    for (int m = 0; m < 4; m++) {
        int pi = pi0 + wr + m*16 + lc;
        const u16* qp = q + ((size_t)(b*SS + NE + pi))*DIM + hh*HD + lg*8;
        af[m][0] = *(const s16x8*)qp;
        af[m][1] = *(const s16x8*)(qp + 32);
    }
    s16x8 bf[4][2];
    #pragma unroll
    for (int n = 0; n < 4; n++) {
        int tau = wc + n*16 + lc;
        const float* ep = (tau < 64) ? (x_emb + (size_t)tau*HD) : (y_emb + (size_t)(tau-64)*HD);
        #pragma unroll
        for (int ks = 0; ks < 2; ks++) {
            const float* e8 = ep + ks*32 + lg*8;
            s16x8 bv;
            #pragma unroll
            for (int t2 = 0; t2 < 8; t2++) bv[t2] = (short)f2b(e8[t2]);
            bf[n][ks] = bv;
        }
    }
    #pragma unroll
    for (int ks = 0; ks < 2; ks++)
        #pragma unroll
        for (int m = 0; m < 4; m++)
            #pragma unroll
            for (int n = 0; n < 4; n++)
                acc[m][n] = __builtin_amdgcn_mfma_f32_16x16x32_bf16(af[m][ks], bf[n][ks], acc[m][n], 0, 0, 0);

    #pragma unroll
    for (int m = 0; m < 4; m++) {
        #pragma unroll
        for (int r = 0; r < 4; r++) {
            int pi = pi0 + wr + m*16 + lg*4 + r;
            int ci = pi & 31, ri = pi >> 5;
            size_t rowbase = ((size_t)bh*SS + NE + pi)*KE;
            #pragma unroll
            for (int n = 0; n < 4; n++) {
                int tau = wc + n*16 + lc;
                float v = acc[m][n][r];
                if (tau < 64) {
                    int c = tau + ci - 32;
                    if (c >= 0 && c < 32) Qe[rowbase + 64 + c] = f2b(v);
                } else {
                    int c = (tau - 64) + ri - 32;
                    if (c >= 0 && c < 32) Qe[rowbase + 96 + c] = f2b(v);
                }
            }
        }
    }
}

// ---------------- flash-style MFMA attention: 64-key tiles + XCD swizzle ----------------
#define KT 64
#define NKT 17
#define NQT 17
__global__ __launch_bounds__(256) void attn_mfma(
    const u16* __restrict__ Qe, const u16* __restrict__ Ke,
    const u16* __restrict__ v, u16* __restrict__ o)
{
    __shared__ __align__(16) u16 Kl[64*192];        // 24 KB
    __shared__ __align__(16) u16 Vt[64][72];        // 9 KB
    __shared__ __align__(16) u16 Pl[4][16][72];     // 9 KB (total 43 KB -> 3 blk/CU)
    int bid = blockIdx.x;
    int g = (bid & 7)*136 + (bid >> 3);
    int qt = g % NQT, bh = g / NQT;
    int b = bh >> 3, hh = bh & 7;
    int tid = threadIdx.x, w = tid>>6, l = tid&63;
    int lg = l>>4, lc = l&15;
    int i0w = qt*64 + w*16;
    const s16x8 zs = {0,0,0,0,0,0,0,0};

    s16x8 qa[5];
    {
        int qrow = i0w + lc; if (qrow > SS-1) qrow = SS-1;
        const u16* qp = Qe + ((size_t)bh*SS + qrow)*KE + lg*8;
        #pragma unroll
        for (int ks = 0; ks < 5; ks++) qa[ks] = *(const s16x8*)(qp + ks*32);
    }

    float m_[4] = {-1e30f, -1e30f, -1e30f, -1e30f};
    float l_[4] = {0.f, 0.f, 0.f, 0.f};
    f32x4 oacc[4];
    #pragma unroll
    for (int f = 0; f < 4; f++) { f32x4 z = {0.f,0.f,0.f,0.f}; oacc[f] = z; }

    int skey = tid & 63, sd0 = (tid >> 6) * 16;

    for (int kt2 = 0; kt2 < NKT; kt2++) {
        int j0 = kt2 * KT;
        #pragma unroll
        for (int p = 0; p < 5; p++) {
            int e = p*256 + tid;
            int row = e / 20, u = e - row*20;
            int j = j0 + row;
            s16x8 kv = zs;
            if (j < SS) kv = *(const s16x8*)(Ke + ((size_t)bh*SS + j)*KE + u*8);
            *(s16x8*)((char*)Kl + row*384 + ((u ^ (row&7)) << 4)) = kv;
        }
        {
            int key = j0 + skey;
            uint4 v0 = {0,0,0,0}, v1 = {0,0,0,0};
            if (key < SS) {
                const uint4* vp = (const uint4*)(v + ((size_t)(b*SS + key))*DIM + hh*HD + sd0);
                v0 = vp[0]; v1 = vp[1];
            }
            const u16* pv = (const u16*)&v0;
            #pragma unroll
            for (int jj = 0; jj < 8; jj++) Vt[sd0 + jj][skey] = pv[jj];
            pv = (const u16*)&v1;
            #pragma unroll
            for (int jj = 0; jj < 8; jj++) Vt[sd0 + 8 + jj][skey] = pv[jj];
        }
        __syncthreads();

        f32x4 s[4];
        #pragma unroll
        for (int f = 0; f < 4; f++) { f32x4 z = {0.f,0.f,0.f,0.f}; s[f] = z; }
        #pragma unroll
        for (int ks = 0; ks < 5; ks++)
            #pragma unroll
            for (int f = 0; f < 4; f++) {
                int row = f*16 + lc;
                s16x8 kb2 = *(const s16x8*)((const char*)Kl + row*384 + ((((ks<<2)+lg) ^ (row&7)) << 4));
                s[f] = __builtin_amdgcn_mfma_f32_16x16x32_bf16(qa[ks], kb2, s[f], 0, 0, 0);
            }

        #pragma unroll
        for (int r = 0; r < 4; r++) {
            #pragma unroll
            for (int f = 0; f < 4; f++) {
                int j = j0 + f*16 + lc;
                if (j >= SS) s[f][r] = -1e30f;
            }
            float t4 = fmaxf(fmaxf(s[0][r], s[1][r]), fmaxf(s[2][r], s[3][r]));
            t4 = fmaxf(t4, __shfl_xor(t4, 1));
            t4 = fmaxf(t4, __shfl_xor(t4, 2));
            t4 = fmaxf(t4, __shfl_xor(t4, 4));
            t4 = fmaxf(t4, __shfl_xor(t4, 8));
            float mn = fmaxf(m_[r], t4);
            float sc = __expf(m_[r] - mn);
            m_[r] = mn;
            float rs = 0.f;
            #pragma unroll
            for (int f = 0; f < 4; f++) {
                float p = __expf(s[f][r] - mn);
                s[f][r] = p;
                rs += p;
            }
            rs += __shfl_xor(rs, 1); rs += __shfl_xor(rs, 2);
            rs += __shfl_xor(rs, 4); rs += __shfl_xor(rs, 8);
            l_[r] = l_[r]*sc + rs;
            #pragma unroll
            for (int f = 0; f < 4; f++) oacc[f][r] *= sc;
        }
        #pragma unroll
        for (int r = 0; r < 4; r++)
            #pragma unroll
            for (int f = 0; f < 4; f++)
                Pl[w][lg*4 + r][f*16 + lc] = f2b(s[f][r]);
        #pragma unroll
        for (int ks = 0; ks < 2; ks++) {
            s16x8 pa = *(const s16x8*)&Pl[w][lc][ks*32 + lg*8];
            #pragma unroll
            for (int f = 0; f < 4; f++) {
                s16x8 vb = *(const s16x8*)&Vt[f*16 + lc][ks*32 + lg*8];
                oacc[f] = __builtin_amdgcn_mfma_f32_16x16x32_bf16(pa, vb, oacc[f], 0, 0, 0);
            }
        }
        __syncthreads();
    }
    #pragma unroll
    for (int r = 0; r < 4; r++) {
        int i = i0w + lg*4 + r;
        if (i >= SS) continue;
        float inv = 1.0f / l_[r];
        #pragma unroll
        for (int f = 0; f < 4; f++)
            o[((size_t)(b*SS + i))*DIM + hh*HD + f*16 + lc] = f2b(oacc[f][r] * inv);
    }
}

// ---------------- classifier ----------------
__global__ void cls_kernel(const float* __restrict__ h, const float* __restrict__ Wc,
                           const float* __restrict__ bc, float* __restrict__ out) {
    int g = blockIdx.x*4 + (threadIdx.x >> 6);
    int lane = threadIdx.x & 63;
    if (g >= BB*S2) return;
    int b = g >> 10, p = g & 1023;
    const float* hr = h + ((size_t)(b*SS + NE + p))*DIM;
    float a0 = 0.f, a1 = 0.f;
    for (int d = lane; d < DIM; d += 64) {
        float hv = hr[d];
        a0 += hv * Wc[d*NC + 0];
        a1 += hv * Wc[d*NC + 1];
    }
    for (int off = 32; off; off >>= 1) { a0 += __shfl_down(a0, off); a1 += __shfl_down(a1, off); }
    if (lane == 0) {
        out[((size_t)(b*NC + 0))*S2 + p] = a0 + bc[0];
        out[((size_t)(b*NC + 1))*S2 + p] = a1 + bc[1];
    }
}

extern "C" void kernel_launch(void* const* d_in, const int* in_sizes, int n_in,
                              void* d_out, int out_size, void* d_ws, size_t ws_size,
                              hipStream_t stream) {
    const float* x      = (const float*)d_in[0];
    const float* patches= (const float*)d_in[1];
    const float* We     = (const float*)d_in[2];
    const float* be     = (const float*)d_in[3];
    const float* x_emb  = (const float*)d_in[4];
    const float* y_emb  = (const float*)d_in[5];
    const float* pad0   = (const float*)d_in[6];
    const float* pad1   = (const float*)d_in[7];
    const float* Wq     = (const float*)d_in[8];
    const float* bq     = (const float*)d_in[9];
    const float* Wk     = (const float*)d_in[10];
    const float* bk     = (const float*)d_in[11];
    const float* Wv     = (const float*)d_in[12];
    const float* bv     = (const float*)d_in[13];
    const float* Wo     = (const float*)d_in[14];
    const float* bo     = (const float*)d_in[15];
    const float* ln1_g  = (const float*)d_in[16];
    const float* ln1_b  = (const float*)d_in[17];
    const float* ln2_g  = (const float*)d_in[18];
    const float* ln2_b  = (const float*)d_in[19];
    const float* W1     = (const float*)d_in[20];
    const float* b1     = (const float*)d_in[21];
    const float* W2     = (const float*)d_in[22];
    const float* b2     = (const float*)d_in[23];
    const float* Wc     = (const float*)d_in[24];
    const float* bc     = (const float*)d_in[25];
    float* out = (float*)d_out;

    float* ws = (float*)d_ws;
    const size_t MD = (size_t)MM*DIM;                  // 4,210,688
    float* h  = ws;                                    // MD f32
    u16* hn   = (u16*)(ws + MD);                       // MD bf16
    u16* qb   = (u16*)(ws + MD + MD/2);                // 4x MD bf16 (q,k,v,o); tb aliases
    u16* kb   = qb + MD;
    u16* vb   = qb + 2*MD;
    u16* ob   = qb + 3*MD;
    u16* tb   = qb;
    u16* Qe   = (u16*)(ws + 3*MD + MD/2);              // EXT u16
    u16* Ke   = Qe + EXT;                              // EXT u16
    float* after = ws + 3*MD + MD/2 + EXT;             // Qe+Ke = 2*EXT u16 = EXT floats
    float* qp0 = after;
    float* qp1 = qp0 + 65792;
    float* bqkv = qp1 + 65792;                         // 1536 f32
    u16* wt   = (u16*)(bqkv + 1536);                   // 6,291,456 u16

    transp_all<<<dim3(1024, 6, LL), 256, 0, stream>>>(Wq, Wk, Wv, Wo, W1, W2, wt);
    embed_kernel<<<MM, 256, 0, stream>>>(x, patches, We, be, h);

    const int extUnits = (int)(EXT / 8);
    const int extBlocks = (extUnits + 255) / 256;

    for (int l = 0; l < LL; l++) {
        u16* base = wt + (size_t)l*WLD;
        cat_bias_kernel<<<6, 256, 0, stream>>>(bq + (size_t)l*DIM, bk + (size_t)l*DIM, bv + (size_t)l*DIM, bqkv);
        ln_kernel<<<MM, 256, 0, stream>>>(h, hn, ln1_g + l*DIM, ln1_b + l*DIM);
        mfma_gemm<2,0><<<65*12, 256, 0, stream>>>(hn, base, bqkv, nullptr, nullptr, qb, kb, vb, MM, 1536, DIM, 12);
        qp_kernel<<<(BB*NH*SS + 255)/256, 256, 0, stream>>>(qb, pad0, pad1, qp0, qp1);
        qext_kernel<<<extBlocks, 256, 0, stream>>>(qb, qp0, qp1, Qe);
        qxy_mfma<<<dim3(8, BB*NH), 256, 0, stream>>>(qb, x_emb, y_emb, Qe);
        kext_kernel<<<extBlocks, 256, 0, stream>>>(kb, Ke);
        attn_mfma<<<NQT*BB*NH, 256, 0, stream>>>(Qe, Ke, vb, ob);
        mfma_gemm_n<<<129*4, 256, 0, stream>>>(ob, base + 786432, bo + (size_t)l*DIM, h, h, MM, DIM, DIM, 4);
        ln_kernel<<<MM, 256, 0, stream>>>(h, hn, ln2_g + l*DIM, ln2_b + l*DIM);
        mfma_gemm<1,1><<<65*16, 256, 0, stream>>>(hn, base + 1048576, b1 + (size_t)l*FFD, nullptr, nullptr, tb, nullptr, nullptr, MM, FFD, DIM, 16);
        mfma_gemm_n<<<129*4, 256, 0, stream>>>(tb, base + 2097152, b2 + (size_t)l*DIM, h, h, MM, DIM, FFD, 4);
    }

    cls_kernel<<<(BB*S2)/4, 256, 0, stream>>>(h, Wc, bc, out);
}